// Round 6
// baseline (1890.881 us; speedup 1.0000x reference)
//
#include <hip/hip_runtime.h>

#define T_LEN 512
#define D_DIM 32
#define N_DIM 64
#define B_ALL 128
#define B_TILE 8
#define SG_PAD 68     // row stride for sH/sG (floats): breaks pow-2 aliasing
#define NTHR 512

typedef float f8 __attribute__((ext_vector_type(8)));

__device__ __forceinline__ float rcp_f(float x) {
#if __has_builtin(__builtin_amdgcn_rcpf)
    return __builtin_amdgcn_rcpf(x);
#else
    return 1.0f / x;
#endif
}
__device__ __forceinline__ float tanh_f(float x) {
    float e = __expf(2.0f * x);
    return 1.0f - 2.0f * rcp_f(e + 1.0f);
}
__device__ __forceinline__ float sig_f(float x) {
    return rcp_f(1.0f + __expf(-x));
}

// Block = (d, 8-batch tile), 512 threads (8 waves), grid = 32*16 = 512.
// W lives in LDS (64 KB) in a swizzled layout so each wave's ds_read_b128 is
// 32 unique CONTIGUOUS 16-B chunks (2-way broadcast over bs_lo) — full-rate,
// conflict-free, and immune to the compiler's register-demotion games that
// made rounds 4/5 L2-BW-bound (VGPR pinned 116, W rematerialized per iter).
// Stage-1 thread (g, bs, no, kg): partial h.W for b={2bs,2bs+1}, n-octet no,
//   k-range kg*16..+15; kg-partials combined via DPP shfl_xor(1|2).
// Stage-3 thread (b3 = tid>>6, n3 = tid&63): adds x*U + bias, gates, c/h,
//   online alpha (full-wave reduce: one wave per b).
__global__ void __launch_bounds__(NTHR, 4)
imv_lstm_scan(const float* __restrict__ x,
              const float* __restrict__ Uj, const float* __restrict__ Ui,
              const float* __restrict__ Uf, const float* __restrict__ Uo,
              const float* __restrict__ Wj, const float* __restrict__ Wi,
              const float* __restrict__ Wf, const float* __restrict__ Wo,
              const float* __restrict__ bj, const float* __restrict__ bi_,
              const float* __restrict__ bf_, const float* __restrict__ bo,
              const float* __restrict__ Fa, const float* __restrict__ Fab,
              const float* __restrict__ Fbw, const float* __restrict__ Fbb,
              const float* __restrict__ Pw, const float* __restrict__ Pb,
              float* __restrict__ wmu, float* __restrict__ wbeta)
{
    // sW layout (float4 units): [(g*16+kl)*64 + half*32 + no*4 + kg]
    //   half=0: W[d][kg*16+kl][no*8 .. +3], half=1: [no*8+4 .. +7]
    __shared__ float4 sW[4 * 16 * 64];        // 64 KB
    __shared__ float  sH[B_TILE][SG_PAD];     // 2.1 KB  h[b][k]
    __shared__ float  sG[4][B_TILE][SG_PAD];  // 8.5 KB  h.W partials

    const int tid = threadIdx.x;
    const int d   = blockIdx.x & 31;
    const int bt  = blockIdx.x >> 5;
    const int bg0 = bt * B_TILE;

    // stage-1 decode: tid = g(2) | bs(2) | no(3) | kg(2)
    const int g  = tid >> 7;
    const int bs = (tid >> 5) & 3;
    const int kg = tid & 3;
    const int no = (tid >> 2) & 7;
    const int r  = tid & 31;          // = no*4 + kg
    const int k0 = kg * 16;
    const int b0 = bs * 2;            // this thread's two b rows: b0, b0+1
    // stage-3 decode
    const int b3 = tid >> 6;          // 0..7, one wave per b
    const int n3 = tid & 63;

    // ---- stage W[d] into LDS, swizzled (one-time, coalesced 16B loads) ----
    for (int i = tid; i < 4096; i += NTHR) {
        int gg = i >> 10, k = (i >> 4) & 63, q = i & 15;
        const float* src = (gg == 0 ? Wj : gg == 1 ? Wi : gg == 2 ? Wf : Wo)
                           + d * (N_DIM * N_DIM) + k * N_DIM + q * 4;
        float4 v = *(const float4*)src;
        int kgg = k >> 4, kll = k & 15, noo = q >> 1, hf = q & 1;
        sW[(gg * 16 + kll) * 64 + hf * 32 + noo * 4 + kgg] = v;
    }
    for (int i = tid; i < B_TILE * SG_PAD; i += NTHR)
        ((float*)sH)[i] = 0.f;

    // stage-3 per-thread params
    const float u_j = Uj[d * N_DIM + n3];
    const float u_i = Ui[d * N_DIM + n3];
    const float u_f = Uf[d * N_DIM + n3];
    const float u_o = Uo[d * N_DIM + n3];
    const float c_j = bj [d * N_DIM + n3];
    const float c_i = bi_[d * N_DIM + n3];
    const float c_f = bf_[d * N_DIM + n3];
    const float c_o = bo [d * N_DIM + n3];
    const float far = Fa[d * N_DIM + n3];
    const float fab = Fab[d];
    const float* xp = x + (size_t)(bg0 + b3) * T_LEN * D_DIM + d;

    __syncthreads();

    float cst = 0.f, hst = 0.f, gacc = 0.f, asum = 0.f;
    const int wbase = g * (16 * 64) + r;

    #pragma unroll 1
    for (int t = 0; t < T_LEN; ++t) {
        float xv = xp[(size_t)t * D_DIM];   // wave-uniform, L1-hot

        // ---------- stage 1: h.W partial (W from LDS, full-rate) ----------
        f8 hA0, hA1, hB0, hB1;
        {
            float4 p0 = *(const float4*)&sH[b0][k0];
            float4 p1 = *(const float4*)&sH[b0][k0 + 4];
            float4 p2 = *(const float4*)&sH[b0][k0 + 8];
            float4 p3 = *(const float4*)&sH[b0][k0 + 12];
            hA0[0]=p0.x; hA0[1]=p0.y; hA0[2]=p0.z; hA0[3]=p0.w;
            hA0[4]=p1.x; hA0[5]=p1.y; hA0[6]=p1.z; hA0[7]=p1.w;
            hA1[0]=p2.x; hA1[1]=p2.y; hA1[2]=p2.z; hA1[3]=p2.w;
            hA1[4]=p3.x; hA1[5]=p3.y; hA1[6]=p3.z; hA1[7]=p3.w;
            float4 q0 = *(const float4*)&sH[b0 + 1][k0];
            float4 q1 = *(const float4*)&sH[b0 + 1][k0 + 4];
            float4 q2 = *(const float4*)&sH[b0 + 1][k0 + 8];
            float4 q3 = *(const float4*)&sH[b0 + 1][k0 + 12];
            hB0[0]=q0.x; hB0[1]=q0.y; hB0[2]=q0.z; hB0[3]=q0.w;
            hB0[4]=q1.x; hB0[5]=q1.y; hB0[6]=q1.z; hB0[7]=q1.w;
            hB1[0]=q2.x; hB1[1]=q2.y; hB1[2]=q2.z; hB1[3]=q2.w;
            hB1[4]=q3.x; hB1[5]=q3.y; hB1[6]=q3.z; hB1[7]=q3.w;
        }
        f8 a0 = {0.f,0.f,0.f,0.f,0.f,0.f,0.f,0.f};
        f8 a1 = {0.f,0.f,0.f,0.f,0.f,0.f,0.f,0.f};

#define KS(KL, HA, HB) { \
        float4 wlo = sW[wbase + (KL) * 64]; \
        float4 whi = sW[wbase + (KL) * 64 + 32]; \
        float h0v = HA[(KL) & 7], h1v = HB[(KL) & 7]; \
        a0[0] = fmaf(h0v, wlo.x, a0[0]); a0[1] = fmaf(h0v, wlo.y, a0[1]); \
        a0[2] = fmaf(h0v, wlo.z, a0[2]); a0[3] = fmaf(h0v, wlo.w, a0[3]); \
        a0[4] = fmaf(h0v, whi.x, a0[4]); a0[5] = fmaf(h0v, whi.y, a0[5]); \
        a0[6] = fmaf(h0v, whi.z, a0[6]); a0[7] = fmaf(h0v, whi.w, a0[7]); \
        a1[0] = fmaf(h1v, wlo.x, a1[0]); a1[1] = fmaf(h1v, wlo.y, a1[1]); \
        a1[2] = fmaf(h1v, wlo.z, a1[2]); a1[3] = fmaf(h1v, wlo.w, a1[3]); \
        a1[4] = fmaf(h1v, whi.x, a1[4]); a1[5] = fmaf(h1v, whi.y, a1[5]); \
        a1[6] = fmaf(h1v, whi.z, a1[6]); a1[7] = fmaf(h1v, whi.w, a1[7]); }
        KS(0,hA0,hB0) KS(1,hA0,hB0) KS(2,hA0,hB0) KS(3,hA0,hB0)
        KS(4,hA0,hB0) KS(5,hA0,hB0) KS(6,hA0,hB0) KS(7,hA0,hB0)
        KS(8,hA1,hB1) KS(9,hA1,hB1) KS(10,hA1,hB1) KS(11,hA1,hB1)
        KS(12,hA1,hB1) KS(13,hA1,hB1) KS(14,hA1,hB1) KS(15,hA1,hB1)
#undef KS

        // combine kg-partials (lane bits 0-1 -> DPP-cheap shfl_xor)
#define CMB(I) { float v0 = a0[I]; v0 += __shfl_xor(v0, 1); v0 += __shfl_xor(v0, 2); a0[I] = v0; \
                 float v1 = a1[I]; v1 += __shfl_xor(v1, 1); v1 += __shfl_xor(v1, 2); a1[I] = v1; }
        CMB(0) CMB(1) CMB(2) CMB(3) CMB(4) CMB(5) CMB(6) CMB(7)
#undef CMB

        // lane kg stores its quarter (constant-index extracts, struct selects)
        {
            int bsel = kg >> 1, half = kg & 1;
            float4 lo0 = make_float4(a0[0], a0[1], a0[2], a0[3]);
            float4 hi0 = make_float4(a0[4], a0[5], a0[6], a0[7]);
            float4 lo1 = make_float4(a1[0], a1[1], a1[2], a1[3]);
            float4 hi1 = make_float4(a1[4], a1[5], a1[6], a1[7]);
            float4 s0 = half ? hi0 : lo0;
            float4 s1 = half ? hi1 : lo1;
            float4 sv = bsel ? s1 : s0;
            *(float4*)&sG[g][b0 + bsel][no * 8 + half * 4] = sv;
        }
        __syncthreads();

        // ---------- stage 3: + x*U + bias, gates, state, online alpha ----------
        float jp = sG[0][b3][n3] + fmaf(xv, u_j, c_j);
        float ip = sG[1][b3][n3] + fmaf(xv, u_i, c_i);
        float fp = sG[2][b3][n3] + fmaf(xv, u_f, c_f);
        float op = sG[3][b3][n3] + fmaf(xv, u_o, c_o);
        float jt = tanh_f(jp);
        float it = sig_f(ip);
        float ft = sig_f(fp);
        float ot = sig_f(op);
        cst = fmaf(cst, ft, it * jt);
        hst = ot * tanh_f(cst);

        float ps = hst * far;
        #pragma unroll
        for (int m = 1; m < 64; m <<= 1)
            ps += __shfl_xor(ps, m);
        float al = __expf(tanh_f(ps + fab));
        asum += al;
        gacc = fmaf(al, hst, gacc);

        sH[b3][n3] = hst;
        __syncthreads();
    }

    // ---------- epilogue: per (b3, d) mu and beta ----------
    float gn  = gacc * (1.0f / asum);
    float pm  = fmaf(gn, Pw[n3],  hst * Pw[64 + n3]);
    float pbv = fmaf(gn, Fbw[n3], hst * Fbw[64 + n3]);
    #pragma unroll
    for (int m = 1; m < 64; m <<= 1) {
        pm  += __shfl_xor(pm, m);
        pbv += __shfl_xor(pbv, m);
    }
    if (n3 == 0) {
        int bglob = bg0 + b3;
        wmu[bglob * D_DIM + d]   = pm + Pb[0];
        wbeta[bglob * D_DIM + d] = __expf(tanh_f(pbv + Fbb[0]));
    }
}

// beta softmax over d + weighted sum -> out[b]
__global__ void imv_finalize(const float* __restrict__ wmu,
                             const float* __restrict__ wbeta,
                             float* __restrict__ out)
{
    int b = blockIdx.x * 64 + threadIdx.x;
    if (b >= B_ALL) return;
    float s1 = 0.f, s2 = 0.f;
    for (int d = 0; d < D_DIM; ++d) {
        float be = wbeta[b * D_DIM + d];
        s1 = fmaf(be, wmu[b * D_DIM + d], s1);
        s2 += be;
    }
    out[b] = s1 / s2;
}

extern "C" void kernel_launch(void* const* d_in, const int* in_sizes, int n_in,
                              void* d_out, int out_size, void* d_ws, size_t ws_size,
                              hipStream_t stream)
{
    const float* x   = (const float*)d_in[0];
    const float* U_j = (const float*)d_in[1];
    const float* U_i = (const float*)d_in[2];
    const float* U_f = (const float*)d_in[3];
    const float* U_o = (const float*)d_in[4];
    const float* W_j = (const float*)d_in[5];
    const float* W_i = (const float*)d_in[6];
    const float* W_f = (const float*)d_in[7];
    const float* W_o = (const float*)d_in[8];
    const float* b_j = (const float*)d_in[9];
    const float* b_i = (const float*)d_in[10];
    const float* b_f = (const float*)d_in[11];
    const float* b_o = (const float*)d_in[12];
    const float* Fan  = (const float*)d_in[13];
    const float* Fanb = (const float*)d_in[14];
    const float* Fbw  = (const float*)d_in[15];
    const float* Fbb  = (const float*)d_in[16];
    const float* Phw  = (const float*)d_in[17];
    const float* Phb  = (const float*)d_in[18];

    float* wmu   = (float*)d_ws;
    float* wbeta = wmu + B_ALL * D_DIM;

    imv_lstm_scan<<<dim3(512), dim3(NTHR), 0, stream>>>(
        x, U_j, U_i, U_f, U_o, W_j, W_i, W_f, W_o,
        b_j, b_i, b_f, b_o, Fan, Fanb, Fbw, Fbb, Phw, Phb,
        wmu, wbeta);

    imv_finalize<<<dim3(2), dim3(64), 0, stream>>>(wmu, wbeta, (float*)d_out);
}

// Round 7
// 1617.817 us; speedup vs baseline: 1.1688x; 1.1688x over previous
//
#include <hip/hip_runtime.h>

#define T_LEN 512
#define D_DIM 32
#define N_DIM 64
#define B_ALL 128
#define B_TILE 8
#define SG_PAD 68     // row stride (floats): 272 B, 16B-aligned, bank-spread
#define NTHR 256

__device__ __forceinline__ float rcp_f(float x) {
#if __has_builtin(__builtin_amdgcn_rcpf)
    return __builtin_amdgcn_rcpf(x);
#else
    return 1.0f / x;
#endif
}
__device__ __forceinline__ float tanh_f(float x) {
    float e = __expf(2.0f * x);
    return 1.0f - 2.0f * rcp_f(e + 1.0f);
}
__device__ __forceinline__ float sig_f(float x) {
    return rcp_f(1.0f + __expf(-x));
}

// Block = (d, 8-batch tile), 256 threads (4 waves), grid = 512, 2 blocks/CU.
// W in LDS [g][k][n] (64 KB). Stage-1 thread (g, bs, n-pair) computes
// pre[g][b0..b0+3][n0..n0+1] over ALL k: 512 FMA per 64 ds_read_b64 of W,
// NO k-split, NO shfl combine (r6's butterfly + 2x W traffic was the stall).
// Stage-3 thread: two (b,n) elements; x prefetched one iter ahead.
__global__ void __launch_bounds__(NTHR, 2)
imv_lstm_scan(const float* __restrict__ x,
              const float* __restrict__ Uj, const float* __restrict__ Ui,
              const float* __restrict__ Uf, const float* __restrict__ Uo,
              const float* __restrict__ Wj, const float* __restrict__ Wi,
              const float* __restrict__ Wf, const float* __restrict__ Wo,
              const float* __restrict__ bj, const float* __restrict__ bi_,
              const float* __restrict__ bf_, const float* __restrict__ bo,
              const float* __restrict__ Fa, const float* __restrict__ Fab,
              const float* __restrict__ Fbw, const float* __restrict__ Fbb,
              const float* __restrict__ Pw, const float* __restrict__ Pb,
              float* __restrict__ wmu, float* __restrict__ wbeta)
{
    __shared__ float sW[4 * N_DIM * N_DIM];   // 64 KB, [g][k][n]
    __shared__ float sH[B_TILE][SG_PAD];      // 2.1 KB
    __shared__ float sG[4][B_TILE][SG_PAD];   // 8.5 KB

    const int tid = threadIdx.x;
    const int d   = blockIdx.x & 31;
    const int bt  = blockIdx.x >> 5;
    const int bg0 = bt * B_TILE;

    // stage-1 decode: tid = g(2) | bs(1) | np(5)
    const int g  = tid >> 6;
    const int ln = tid & 63;
    const int np = ln & 31;
    const int bs = ln >> 5;
    const int n0 = np * 2;
    const int b0 = bs * 4;
    // stage-3 decode: elements (b3, n3) and (b3+4, n3)
    const int b3 = tid >> 6;
    const int n3 = tid & 63;

    // ---- stage W[d] into LDS (plain [g][k][n], coalesced float4) ----
    for (int i = tid; i < 4096; i += NTHR) {
        int gg = i >> 10, rem = i & 1023, k = rem >> 4, q = rem & 15;
        const float* src = (gg == 0 ? Wj : gg == 1 ? Wi : gg == 2 ? Wf : Wo)
                           + d * (N_DIM * N_DIM) + k * N_DIM + q * 4;
        *(float4*)&sW[gg * 4096 + k * N_DIM + q * 4] = *(const float4*)src;
    }
    for (int i = tid; i < B_TILE * SG_PAD; i += NTHR)
        ((float*)sH)[i] = 0.f;

    // stage-3 per-thread params (shared by both elements: same n3, same d)
    const int dn = d * N_DIM + n3;
    const float u_j = Uj[dn], u_i = Ui[dn], u_f = Uf[dn], u_o = Uo[dn];
    const float cbj = bj[dn], cbi = bi_[dn], cbf = bf_[dn], cbo = bo[dn];
    const float far = Fa[dn];
    const float fab = Fab[d];
    const float* xq0 = x + (size_t)(bg0 + b3) * T_LEN * D_DIM + d;
    const float* xq1 = x + (size_t)(bg0 + b3 + 4) * T_LEN * D_DIM + d;

    __syncthreads();

    float cs0 = 0.f, hs0 = 0.f, cs1 = 0.f, hs1 = 0.f;
    float ga0 = 0.f, as0 = 0.f, ga1 = 0.f, as1 = 0.f;
    const float* wcol = sW + g * 4096 + n0;

    float xc0 = xq0[0];
    float xc1 = xq1[0];

    #pragma unroll 1
    for (int t = 0; t < T_LEN; ++t) {
        // prefetch next-iter x (used after two barriers -> latency hidden)
        float xn0 = 0.f, xn1 = 0.f;
        if (t + 1 < T_LEN) {
            xn0 = xq0[(size_t)(t + 1) * D_DIM];
            xn1 = xq1[(size_t)(t + 1) * D_DIM];
        }

        // ---------- stage 1: pre[g][b0..+3][n0..+1] over all k ----------
        float2 a0 = {0.f, 0.f}, a1 = {0.f, 0.f};
        float2 a2 = {0.f, 0.f}, a3 = {0.f, 0.f};
        #pragma unroll
        for (int k4 = 0; k4 < 16; ++k4) {
            float4 hv0 = *(const float4*)&sH[b0 + 0][k4 * 4];
            float4 hv1 = *(const float4*)&sH[b0 + 1][k4 * 4];
            float4 hv2 = *(const float4*)&sH[b0 + 2][k4 * 4];
            float4 hv3 = *(const float4*)&sH[b0 + 3][k4 * 4];
            float hb0[4] = {hv0.x, hv0.y, hv0.z, hv0.w};
            float hb1[4] = {hv1.x, hv1.y, hv1.z, hv1.w};
            float hb2[4] = {hv2.x, hv2.y, hv2.z, hv2.w};
            float hb3[4] = {hv3.x, hv3.y, hv3.z, hv3.w};
            #pragma unroll
            for (int kk = 0; kk < 4; ++kk) {
                float2 w = *(const float2*)(wcol + (k4 * 4 + kk) * N_DIM);
                a0.x = fmaf(hb0[kk], w.x, a0.x); a0.y = fmaf(hb0[kk], w.y, a0.y);
                a1.x = fmaf(hb1[kk], w.x, a1.x); a1.y = fmaf(hb1[kk], w.y, a1.y);
                a2.x = fmaf(hb2[kk], w.x, a2.x); a2.y = fmaf(hb2[kk], w.y, a2.y);
                a3.x = fmaf(hb3[kk], w.x, a3.x); a3.y = fmaf(hb3[kk], w.y, a3.y);
            }
        }
        *(float2*)&sG[g][b0 + 0][n0] = a0;
        *(float2*)&sG[g][b0 + 1][n0] = a1;
        *(float2*)&sG[g][b0 + 2][n0] = a2;
        *(float2*)&sG[g][b0 + 3][n0] = a3;
        __syncthreads();

        // ---------- stage 3: two (b,n) elements ----------
        float jp0 = sG[0][b3][n3] + fmaf(xc0, u_j, cbj);
        float ip0 = sG[1][b3][n3] + fmaf(xc0, u_i, cbi);
        float fp0 = sG[2][b3][n3] + fmaf(xc0, u_f, cbf);
        float op0 = sG[3][b3][n3] + fmaf(xc0, u_o, cbo);
        float jp1 = sG[0][b3 + 4][n3] + fmaf(xc1, u_j, cbj);
        float ip1 = sG[1][b3 + 4][n3] + fmaf(xc1, u_i, cbi);
        float fp1 = sG[2][b3 + 4][n3] + fmaf(xc1, u_f, cbf);
        float op1 = sG[3][b3 + 4][n3] + fmaf(xc1, u_o, cbo);

        float jt0 = tanh_f(jp0), it0 = sig_f(ip0);
        float ft0 = sig_f(fp0),  ot0 = sig_f(op0);
        float jt1 = tanh_f(jp1), it1 = sig_f(ip1);
        float ft1 = sig_f(fp1),  ot1 = sig_f(op1);
        cs0 = fmaf(cs0, ft0, it0 * jt0);
        cs1 = fmaf(cs1, ft1, it1 * jt1);
        hs0 = ot0 * tanh_f(cs0);
        hs1 = ot1 * tanh_f(cs1);

        float ps0 = hs0 * far;
        float ps1 = hs1 * far;
        #pragma unroll
        for (int m = 1; m < 64; m <<= 1) {
            ps0 += __shfl_xor(ps0, m);
            ps1 += __shfl_xor(ps1, m);
        }
        float al0 = __expf(tanh_f(ps0 + fab));
        float al1 = __expf(tanh_f(ps1 + fab));
        as0 += al0; ga0 = fmaf(al0, hs0, ga0);
        as1 += al1; ga1 = fmaf(al1, hs1, ga1);

        sH[b3][n3]     = hs0;
        sH[b3 + 4][n3] = hs1;
        __syncthreads();

        xc0 = xn0; xc1 = xn1;
    }

    // ---------- epilogue: per (b,d) mu and beta for both elements ----------
    float pw0v = Pw[n3],  pw1v = Pw[64 + n3];
    float fw0v = Fbw[n3], fw1v = Fbw[64 + n3];
    float gn0 = ga0 * (1.0f / as0);
    float gn1 = ga1 * (1.0f / as1);
    float pm0 = fmaf(gn0, pw0v, hs0 * pw1v);
    float pb0 = fmaf(gn0, fw0v, hs0 * fw1v);
    float pm1 = fmaf(gn1, pw0v, hs1 * pw1v);
    float pb1 = fmaf(gn1, fw0v, hs1 * fw1v);
    #pragma unroll
    for (int m = 1; m < 64; m <<= 1) {
        pm0 += __shfl_xor(pm0, m);
        pb0 += __shfl_xor(pb0, m);
        pm1 += __shfl_xor(pm1, m);
        pb1 += __shfl_xor(pb1, m);
    }
    if (n3 == 0) {
        wmu  [(bg0 + b3) * D_DIM + d]     = pm0 + Pb[0];
        wbeta[(bg0 + b3) * D_DIM + d]     = __expf(tanh_f(pb0 + Fbb[0]));
        wmu  [(bg0 + b3 + 4) * D_DIM + d] = pm1 + Pb[0];
        wbeta[(bg0 + b3 + 4) * D_DIM + d] = __expf(tanh_f(pb1 + Fbb[0]));
    }
}

// beta softmax over d + weighted sum -> out[b]
__global__ void imv_finalize(const float* __restrict__ wmu,
                             const float* __restrict__ wbeta,
                             float* __restrict__ out)
{
    int b = blockIdx.x * 64 + threadIdx.x;
    if (b >= B_ALL) return;
    float s1 = 0.f, s2 = 0.f;
    for (int d = 0; d < D_DIM; ++d) {
        float be = wbeta[b * D_DIM + d];
        s1 = fmaf(be, wmu[b * D_DIM + d], s1);
        s2 += be;
    }
    out[b] = s1 / s2;
}

extern "C" void kernel_launch(void* const* d_in, const int* in_sizes, int n_in,
                              void* d_out, int out_size, void* d_ws, size_t ws_size,
                              hipStream_t stream)
{
    const float* x   = (const float*)d_in[0];
    const float* U_j = (const float*)d_in[1];
    const float* U_i = (const float*)d_in[2];
    const float* U_f = (const float*)d_in[3];
    const float* U_o = (const float*)d_in[4];
    const float* W_j = (const float*)d_in[5];
    const float* W_i = (const float*)d_in[6];
    const float* W_f = (const float*)d_in[7];
    const float* W_o = (const float*)d_in[8];
    const float* b_j = (const float*)d_in[9];
    const float* b_i = (const float*)d_in[10];
    const float* b_f = (const float*)d_in[11];
    const float* b_o = (const float*)d_in[12];
    const float* Fan  = (const float*)d_in[13];
    const float* Fanb = (const float*)d_in[14];
    const float* Fbw  = (const float*)d_in[15];
    const float* Fbb  = (const float*)d_in[16];
    const float* Phw  = (const float*)d_in[17];
    const float* Phb  = (const float*)d_in[18];

    float* wmu   = (float*)d_ws;
    float* wbeta = wmu + B_ALL * D_DIM;

    imv_lstm_scan<<<dim3(512), dim3(NTHR), 0, stream>>>(
        x, U_j, U_i, U_f, U_o, W_j, W_i, W_f, W_o,
        b_j, b_i, b_f, b_o, Fan, Fanb, Fbw, Fbb, Phw, Phb,
        wmu, wbeta);

    imv_finalize<<<dim3(2), dim3(64), 0, stream>>>(wmu, wbeta, (float*)d_out);
}